// Round 8
// baseline (801.929 us; speedup 1.0000x reference)
//
#include <hip/hip_runtime.h>

#define NPTS 4096
#define NQ   1024
#define NB   8
#define XTW  36            // sa LDS row stride (floats): 144B = 9*16B

#define FPS_T  512
#define FPW    4               // working waves in fps blocks (waves 0..3)
#define SLOTS  16              // points per thread (t in [0,256))
#define FPS_NB 8               // fps blocks (one per batch)
#define WRK_NB 240             // persistent worker blocks
#define NWRK   (WRK_NB * 8)    // 1920 worker waves
#define WSLICE 10496           // per-wave worker LDS slice (>= 9648 XT + 128 bidx)
#define SMEM_BYTES (WSLICE * 8) // 83968 B: 2x > 160KiB => exactly 1 block/CU

// ===========================================================================
// DPP helpers
// ===========================================================================
template <int CTRL, int RM>
__device__ __forceinline__ float dppf(float v) {
  return __int_as_float(__builtin_amdgcn_update_dpp(
      __float_as_int(v), __float_as_int(v), CTRL, RM, 0xf, false));
}

__device__ __forceinline__ float wave_max_f(float v) {
  v = fmaxf(v, dppf<0x111, 0xf>(v));   // row_shr:1
  v = fmaxf(v, dppf<0x112, 0xf>(v));   // row_shr:2
  v = fmaxf(v, dppf<0x114, 0xf>(v));   // row_shr:4
  v = fmaxf(v, dppf<0x118, 0xf>(v));   // row_shr:8
  v = fmaxf(v, dppf<0x142, 0xa>(v));   // row_bcast:15
  v = fmaxf(v, dppf<0x143, 0xc>(v));   // row_bcast:31 -> lane 63 valid
  return v;
}

template <int C>
__device__ __forceinline__ float dppq(float v) {
  return __int_as_float(__builtin_amdgcn_update_dpp(
      __float_as_int(v), __float_as_int(v), C, 0xf, 0xf, false));
}

// ===========================================================================
// FPS role (blocks 0..7).  4 working waves x 16 slots/lane; waves 4..7 only
// hit the barrier.  Reduction: f32 max3 tree + DPP-fused f32 wave max, index
// recovered by ballots vs the broadcast max (k-descending scan => lowest
// original index, identical tie-break to the u64-key method).  Cross-wave
// merge via 4 u64 keys (f64 max, sign bit 0 — established r7).  Publish is
// batched 8-at-a-time so the store drain sits a full iteration off the
// barrier's vmcnt(0) path.
// ===========================================================================
__device__ void fps_role(const float* __restrict__ xyz,
                         float* __restrict__ out_newxyz,
                         int* __restrict__ ws_idx, char* smem)
{
  const int b    = blockIdx.x;
  const int t    = threadIdx.x;        // 0..511
  const int lane = t & 63;
  const int wave = t >> 6;

  float* sxyz4 = (float*)smem;                       // 64 KB padded xyz
  double (*swk)[FPW] = (double(*)[FPW])(smem + NPTS * 16);  // [2][4]

  const float* xb = xyz + (size_t)b * NPTS * 3;
  for (int p = t; p < NPTS; p += FPS_T) {
    sxyz4[p * 4 + 0] = xb[p * 3 + 0];
    sxyz4[p * 4 + 1] = xb[p * 3 + 1];
    sxyz4[p * 4 + 2] = xb[p * 3 + 2];
    sxyz4[p * 4 + 3] = 0.0f;
  }
  __syncthreads();

  float px[SLOTS], py[SLOTS], pz[SLOTS], dst[SLOTS];
  if (wave < FPW) {
#pragma unroll
    for (int k = 0; k < SLOTS; ++k) {
      int p = t + (k << 8);            // t in [0,256): p-major in k
      px[k] = sxyz4[p * 4 + 0];
      py[k] = sxyz4[p * 4 + 1];
      pz[k] = sxyz4[p * 4 + 2];
      dst[k] = 1e10f;                  // matches reference init 1e10
    }
  }

  int far = 0;                         // reference: farthest starts at 0
  int fkeep = 0;                       // wave0 publish FIFO (1 word/lane)
  int farh[4] = {0, 0, 0, 0};          // newxyz history (4 rows/thread)

  for (int n = 0; n < NQ; ++n) {
    if (wave < FPW) {
      const float4 c = *(const float4*)(sxyz4 + far * 4);   // broadcast b128
      if (wave == 0 && lane == (n & 7)) fkeep = far;
      if ((n & 255) == t) farh[n >> 8] = far;

#pragma unroll
      for (int k = 0; k < SLOTS; ++k) {
        // EXACT reference order: (dx*dx + dy*dy) + dz*dz, no FMA contraction
        float dx = __fsub_rn(px[k], c.x);
        float dy = __fsub_rn(py[k], c.y);
        float dz = __fsub_rn(pz[k], c.z);
        float d2 = __fadd_rn(__fadd_rn(__fmul_rn(dx, dx), __fmul_rn(dy, dy)),
                             __fmul_rn(dz, dz));
        dst[k] = fminf(dst[k], d2);
      }
      // in-lane max tree (v_max3_f32): 16 -> 1 in 8 ops
      float m0 = fmaxf(fmaxf(dst[0],  dst[1]),  dst[2]);
      float m1 = fmaxf(fmaxf(dst[3],  dst[4]),  dst[5]);
      float m2 = fmaxf(fmaxf(dst[6],  dst[7]),  dst[8]);
      float m3 = fmaxf(fmaxf(dst[9],  dst[10]), dst[11]);
      float m4 = fmaxf(fmaxf(dst[12], dst[13]), dst[14]);
      float ma = fmaxf(fmaxf(m0, m1), m2);
      float mb = fmaxf(fmaxf(m3, m4), dst[15]);
      float m  = fmaxf(ma, mb);
      m = wave_max_f(m);               // lane 63 has wave max
      const float ms = __int_as_float(
          __builtin_amdgcn_readlane(__float_as_int(m), 63));

      // argmax index: k descending, ctz(ballot) => lowest original p
      int idxw = 0;
#pragma unroll
      for (int k = SLOTS - 1; k >= 0; --k) {
        unsigned long long mask = __ballot(dst[k] == ms);
        if (mask) idxw = (k << 8) + (wave << 6) + (int)__builtin_ctzll(mask);
      }
      // wave key: (ms_bits<<32)|~idx — f64-max-safe (sign bit 0, r7 analysis)
      if (lane == 0) {
        unsigned long long kb =
            ((unsigned long long)__float_as_uint(ms) << 32) |
            (unsigned)(~(unsigned)idxw);
        swk[n & 1][wave] = __longlong_as_double((long long)kb);
      }
    }
    __syncthreads();
    if (wave < FPW) {
      const double2* sp = (const double2*)swk[n & 1];
      double2 a0 = sp[0], a1 = sp[1];
      double mk = fmax(fmax(a0.x, a0.y), fmax(a1.x, a1.y));
      far = (int)(~(unsigned)((unsigned long long)__double_as_longlong(mk)));
      // batched publish: 8 indices, drain lands a full iteration from the
      // next barrier -> off the critical path
      if (wave == 0 && lane < 8 && (n & 7) == 7)
        __hip_atomic_store(ws_idx + (b << 10) + (n & ~7) + lane, fkeep,
                           __ATOMIC_RELAXED, __HIP_MEMORY_SCOPE_AGENT);
    }
  }

  // write all 1024 centroids once (bit-exact copies of input rows)
  if (wave < FPW) {
#pragma unroll
    for (int j = 0; j < 4; ++j) {
      float4 c = *(const float4*)(sxyz4 + farh[j] * 4);
      float* o = out_newxyz + ((size_t)b * NQ + (j << 8) + t) * 3;
      o[0] = c.x; o[1] = c.y; o[2] = c.z;
    }
  }
}

// ===========================================================================
// SA per-query machinery (unchanged from r7 — known correct)
// ===========================================================================
__device__ __forceinline__ void mlp_acc(float* __restrict__ acc,
                                        const float* __restrict__ XTb,
                                        const float* __restrict__ wg,
                                        int ldw, int nk, int fg, int sg)
{
#pragma unroll
  for (int i = 0; i < 32; ++i) acc[i] = 0.0f;
  const float* xrow = XTb + sg * 4;
  const float* wrow = wg + fg * 8;
#pragma unroll 4
  for (int k = 0; k < nk; ++k) {
    const float4 x  = *(const float4*)(xrow + k * XTW);
    const float4 wa = *(const float4*)(wrow + (size_t)k * ldw);
    const float4 wb = *(const float4*)(wrow + (size_t)k * ldw + 4);
    acc[0]  = fmaf(wa.x, x.x, acc[0]);  acc[1]  = fmaf(wa.x, x.y, acc[1]);
    acc[2]  = fmaf(wa.x, x.z, acc[2]);  acc[3]  = fmaf(wa.x, x.w, acc[3]);
    acc[4]  = fmaf(wa.y, x.x, acc[4]);  acc[5]  = fmaf(wa.y, x.y, acc[5]);
    acc[6]  = fmaf(wa.y, x.z, acc[6]);  acc[7]  = fmaf(wa.y, x.w, acc[7]);
    acc[8]  = fmaf(wa.z, x.x, acc[8]);  acc[9]  = fmaf(wa.z, x.y, acc[9]);
    acc[10] = fmaf(wa.z, x.z, acc[10]); acc[11] = fmaf(wa.z, x.w, acc[11]);
    acc[12] = fmaf(wa.w, x.x, acc[12]); acc[13] = fmaf(wa.w, x.y, acc[13]);
    acc[14] = fmaf(wa.w, x.z, acc[14]); acc[15] = fmaf(wa.w, x.w, acc[15]);
    acc[16] = fmaf(wb.x, x.x, acc[16]); acc[17] = fmaf(wb.x, x.y, acc[17]);
    acc[18] = fmaf(wb.x, x.z, acc[18]); acc[19] = fmaf(wb.x, x.w, acc[19]);
    acc[20] = fmaf(wb.y, x.x, acc[20]); acc[21] = fmaf(wb.y, x.y, acc[21]);
    acc[22] = fmaf(wb.y, x.z, acc[22]); acc[23] = fmaf(wb.y, x.w, acc[23]);
    acc[24] = fmaf(wb.z, x.x, acc[24]); acc[25] = fmaf(wb.z, x.y, acc[25]);
    acc[26] = fmaf(wb.z, x.z, acc[26]); acc[27] = fmaf(wb.z, x.w, acc[27]);
    acc[28] = fmaf(wb.w, x.x, acc[28]); acc[29] = fmaf(wb.w, x.y, acc[29]);
    acc[30] = fmaf(wb.w, x.z, acc[30]); acc[31] = fmaf(wb.w, x.w, acc[31]);
  }
}

__device__ __forceinline__ void store_layer(const float* __restrict__ acc,
                                            float* __restrict__ XTb,
                                            const float* __restrict__ g,
                                            const float* __restrict__ bi,
                                            const float* __restrict__ be,
                                            int fg, int sg, float RSQ)
{
  const float4 ga = *(const float4*)(g  + fg * 8);
  const float4 gb = *(const float4*)(g  + fg * 8 + 4);
  const float4 ba = *(const float4*)(bi + fg * 8);
  const float4 bb = *(const float4*)(bi + fg * 8 + 4);
  const float4 ea = *(const float4*)(be + fg * 8);
  const float4 eb = *(const float4*)(be + fg * 8 + 4);
  float sv[8] = {ga.x * RSQ, ga.y * RSQ, ga.z * RSQ, ga.w * RSQ,
                 gb.x * RSQ, gb.y * RSQ, gb.z * RSQ, gb.w * RSQ};
  float bv[8] = {ba.x, ba.y, ba.z, ba.w, bb.x, bb.y, bb.z, bb.w};
  float ev[8] = {ea.x, ea.y, ea.z, ea.w, eb.x, eb.y, eb.z, eb.w};
#pragma unroll
  for (int j = 0; j < 8; ++j) {
    float tv = fmaf(bv[j], sv[j], ev[j]);
    float4 h;
    h.x = fmaxf(fmaf(acc[j * 4 + 0], sv[j], tv), 0.0f);
    h.y = fmaxf(fmaf(acc[j * 4 + 1], sv[j], tv), 0.0f);
    h.z = fmaxf(fmaf(acc[j * 4 + 2], sv[j], tv), 0.0f);
    h.w = fmaxf(fmaf(acc[j * 4 + 3], sv[j], tv), 0.0f);
    *(float4*)(XTb + (fg * 8 + j) * XTW + sg * 4) = h;
  }
}

__device__ void worker_query(int q, int idx,
    const float* __restrict__ xyz, const float* __restrict__ pts,
    const float* __restrict__ w0, const float* __restrict__ b0,
    const float* __restrict__ g0, const float* __restrict__ be0,
    const float* __restrict__ w1, const float* __restrict__ b1,
    const float* __restrict__ g1, const float* __restrict__ be1,
    const float* __restrict__ w2, const float* __restrict__ b2,
    const float* __restrict__ g2, const float* __restrict__ be2,
    float* __restrict__ outp, float* __restrict__ XT, int* __restrict__ bidx,
    int lane)
{
  const int b = q >> 10;
  const float* xb = xyz + (size_t)b * NPTS * 3;
  // centroid from the immutable input via the published index: bit-identical
  // to newxyz[q], immune to cache staleness (xyz never written on GPU).
  const float cx = xb[idx * 3 + 0];
  const float cy = xb[idx * 3 + 1];
  const float cz = xb[idx * 3 + 2];

  // ---- ball query (pipelined 2 ahead): first <=32 in-radius, ascending ----
  int cnt = 0;
  float x0 = xb[lane * 3 + 0], y0 = xb[lane * 3 + 1], z0 = xb[lane * 3 + 2];
  float x1 = xb[(64 + lane) * 3 + 0], y1 = xb[(64 + lane) * 3 + 1],
        z1 = xb[(64 + lane) * 3 + 2];
  for (int ch = 0; ch < 64; ++ch) {
    const int an = (min(ch + 2, 63) << 6) | lane;
    float nx = xb[an * 3 + 0], ny = xb[an * 3 + 1], nz = xb[an * 3 + 2];
    float dx = __fsub_rn(cx, x0);
    float dy = __fsub_rn(cy, y0);
    float dz = __fsub_rn(cz, z0);
    float d2 = __fadd_rn(__fadd_rn(__fmul_rn(dx, dx), __fmul_rn(dy, dy)),
                         __fmul_rn(dz, dz));
    bool in = d2 < 0.04f;
    unsigned long long bal = __ballot(in);
    int pos = cnt + (int)__popcll(bal & ((1ull << lane) - 1ull));
    if (in && pos < 32) bidx[pos] = (ch << 6) | lane;
    cnt += (int)__popcll(bal);
    x0 = x1; y0 = y1; z0 = z1;
    x1 = nx; y1 = ny; z1 = nz;
    if (cnt >= 32) break;
  }
  if (cnt > 32) cnt = 32;
  int i0 = bidx[0];
  if (lane < 32 && lane >= cnt) bidx[lane] = i0;
  __builtin_amdgcn_wave_barrier();

  // ---- gather into X^T[k][s] ----
  const int s  = lane & 31;
  const int kc = lane >> 5;
  const int is = bidx[s];
  const float4* pr4 = (const float4*)(pts + ((size_t)(b * NPTS + is)) * 64 + kc * 32);
  float* xcol = XT + s;
#pragma unroll
  for (int c = 0; c < 8; ++c) {
    float4 v = pr4[c];
    xcol[(kc * 32 + c * 4 + 0) * XTW] = v.x;
    xcol[(kc * 32 + c * 4 + 1) * XTW] = v.y;
    xcol[(kc * 32 + c * 4 + 2) * XTW] = v.z;
    xcol[(kc * 32 + c * 4 + 3) * XTW] = v.w;
  }
  if (kc == 0) {
    float ax = xb[is * 3 + 0], ay = xb[is * 3 + 1], az = xb[is * 3 + 2];
    xcol[64 * XTW] = ax - cx;
    xcol[65 * XTW] = ay - cy;
    xcol[66 * XTW] = az - cz;
  }
  __builtin_amdgcn_wave_barrier();

  const int fg = lane >> 3;
  const int sg = lane & 7;
  const float RSQ = rsqrtf(1.0f + 0.001f);
  float acc[32];

  mlp_acc(acc, XT, w0, 64, 67, fg, sg);
  store_layer(acc, XT, g0, b0, be0, fg, sg, RSQ);
  __builtin_amdgcn_wave_barrier();

  mlp_acc(acc, XT, w1, 64, 64, fg, sg);
  store_layer(acc, XT, g1, b1, be1, fg, sg, RSQ);
  __builtin_amdgcn_wave_barrier();

#pragma unroll
  for (int pass = 0; pass < 2; ++pass) {
    const int fofs = pass << 6;
    mlp_acc(acc, XT, w2 + fofs, 128, 64, fg, sg);
    const float4 ga = *(const float4*)(g2  + fofs + fg * 8);
    const float4 gb = *(const float4*)(g2  + fofs + fg * 8 + 4);
    const float4 ba = *(const float4*)(b2  + fofs + fg * 8);
    const float4 bb = *(const float4*)(b2  + fofs + fg * 8 + 4);
    const float4 ea = *(const float4*)(be2 + fofs + fg * 8);
    const float4 eb = *(const float4*)(be2 + fofs + fg * 8 + 4);
    float sv[8] = {ga.x * RSQ, ga.y * RSQ, ga.z * RSQ, ga.w * RSQ,
                   gb.x * RSQ, gb.y * RSQ, gb.z * RSQ, gb.w * RSQ};
    float bv[8] = {ba.x, ba.y, ba.z, ba.w, bb.x, bb.y, bb.z, bb.w};
    float ev[8] = {ea.x, ea.y, ea.z, ea.w, eb.x, eb.y, eb.z, eb.w};
    float r[8];
#pragma unroll
    for (int j = 0; j < 8; ++j) {
      float mx = fmaxf(fmaxf(acc[j * 4 + 0], acc[j * 4 + 1]),
                       fmaxf(acc[j * 4 + 2], acc[j * 4 + 3]));
      float mn = fminf(fminf(acc[j * 4 + 0], acc[j * 4 + 1]),
                       fminf(acc[j * 4 + 2], acc[j * 4 + 3]));
      mx = fmaxf(mx, dppq<0xB1>(mx));
      mx = fmaxf(mx, dppq<0x4E>(mx));
      mx = fmaxf(mx, dppq<0x141>(mx));
      mn = fminf(mn, dppq<0xB1>(mn));
      mn = fminf(mn, dppq<0x4E>(mn));
      mn = fminf(mn, dppq<0x141>(mn));
      float tv = fmaf(bv[j], sv[j], ev[j]);
      float m  = (sv[j] >= 0.0f) ? mx : mn;    // maxpool commutes with affine
      r[j] = fmaxf(fmaf(sv[j], m, tv), 0.0f);
    }
    if (sg == 0) {
      float* o = outp + (size_t)q * 128 + fofs + fg * 8;
      *(float4*)(o)     = make_float4(r[0], r[1], r[2], r[3]);
      *(float4*)(o + 4) = make_float4(r[4], r[5], r[6], r[7]);
    }
  }
}

// ===========================================================================
// Fused kernel: 248 blocks x 512 thr, 84 KB LDS => 1 block/CU => all blocks
// co-resident regardless of dispatch order (deadlock-impossible).  Blocks
// 0..7: FPS.  Blocks 8..247: 8 persistent worker waves; spin (s_sleep,
// bounded) on the published index then run ball-query+MLP.
// ===========================================================================
__global__ __launch_bounds__(FPS_T, 1) void fused_kernel(
    const float* __restrict__ xyz, const float* __restrict__ pts,
    const float* __restrict__ w0, const float* __restrict__ b0,
    const float* __restrict__ g0, const float* __restrict__ be0,
    const float* __restrict__ w1, const float* __restrict__ b1,
    const float* __restrict__ g1, const float* __restrict__ be1,
    const float* __restrict__ w2, const float* __restrict__ b2,
    const float* __restrict__ g2, const float* __restrict__ be2,
    float* __restrict__ newxyz, float* __restrict__ newpts,
    int* __restrict__ ws_idx)
{
  __shared__ __align__(16) char smem[SMEM_BYTES];

  if (blockIdx.x < FPS_NB) {
    fps_role(xyz, newxyz, ws_idx, smem);
    return;
  }

  const int lane = threadIdx.x & 63;
  const int wave = threadIdx.x >> 6;
  char* sl = smem + wave * WSLICE;
  float* XT  = (float*)sl;           // 67*36*4 = 9648 B
  int* bidx  = (int*)(sl + 9648);    // 128 B

  const int W = (blockIdx.x - FPS_NB) * 8 + wave;
  for (int g = W; g < NB * NQ; g += NWRK) {
    const int b = g & 7;
    const int n = g >> 3;
    const int q = (b << 10) | n;

    const int* slot = ws_idx + q;
    int idx = __hip_atomic_load(slot, __ATOMIC_RELAXED, __HIP_MEMORY_SCOPE_AGENT);
    int spins = 0;
    while ((unsigned)idx >= (unsigned)NPTS) {       // sentinel/poison = wait
      __builtin_amdgcn_s_sleep(16);
      idx = __hip_atomic_load(slot, __ATOMIC_RELAXED, __HIP_MEMORY_SCOPE_AGENT);
      if (++spins > 32768) { idx &= (NPTS - 1); break; }  // bounded: no hang
    }

    worker_query(q, idx, xyz, pts, w0, b0, g0, be0, w1, b1, g1, be1,
                 w2, b2, g2, be2, newpts, XT, bidx, lane);
  }
}

// ===========================================================================
extern "C" void kernel_launch(void* const* d_in, const int* in_sizes, int n_in,
                              void* d_out, int out_size, void* d_ws, size_t ws_size,
                              hipStream_t stream)
{
  const float* xyz = (const float*)d_in[0];
  const float* pts = (const float*)d_in[1];
  const float* w0  = (const float*)d_in[2];
  const float* b0  = (const float*)d_in[3];
  const float* g0  = (const float*)d_in[4];
  const float* be0 = (const float*)d_in[5];
  const float* w1  = (const float*)d_in[6];
  const float* b1  = (const float*)d_in[7];
  const float* g1  = (const float*)d_in[8];
  const float* be1 = (const float*)d_in[9];
  const float* w2  = (const float*)d_in[10];
  const float* b2  = (const float*)d_in[11];
  const float* g2  = (const float*)d_in[12];
  const float* be2 = (const float*)d_in[13];

  float* out    = (float*)d_out;
  float* newxyz = out;                    // 8*1024*3
  float* newpts = out + NB * NQ * 3;      // 8*1024*128
  int*   ws_idx = (int*)d_ws;             // 8192 published indices

  // sentinel-fill the mailbox (0xAA... is an invalid index)
  hipMemsetAsync(d_ws, 0xAA, (size_t)NB * NQ * sizeof(int), stream);

  hipLaunchKernelGGL(fused_kernel, dim3(FPS_NB + WRK_NB), dim3(FPS_T), 0, stream,
                     xyz, pts, w0, b0, g0, be0, w1, b1, g1, be1,
                     w2, b2, g2, be2, newxyz, newpts, ws_idx);
}

// Round 9
// 736.027 us; speedup vs baseline: 1.0895x; 1.0895x over previous
//
#include <hip/hip_runtime.h>

#define NPTS 4096
#define NQ   1024
#define NB   8
#define XTW  36            // sa LDS row stride (floats): 144B = 9*16B

#define FPS_T  512
#define FPS_W  8               // 8 working waves (2/SIMD — latency hiding, r8 lesson)
#define FPS_NB 8               // fps blocks (one per batch)
#define WRK_NB 240             // persistent worker blocks
#define NWRK   (WRK_NB * 8)    // 1920 worker waves
#define WSLICE 10496           // per-wave worker LDS slice (>= 9648 XT + 128 bidx)
#define SMEM_BYTES (WSLICE * 8) // 83968 B: 2x > 160KiB => exactly 1 block/CU

typedef float f32x2 __attribute__((ext_vector_type(2)));

// ===========================================================================
// DPP + f64-key helpers (r7-proven).  FPS keys: (dst_bits<<32)|~idx, sign
// bit always 0; v_max_f64 == u64 max here (hi word is an f32 bit pattern in
// [0,1e10] => exponent never all-ones => never NaN; denormal-f64 keys only
// for dst==0 = already-selected points which can never win).  Unique idx =>
// no ties.  Bit-exact argmax, lowest-original-index tie-break.
// ===========================================================================
template <int CTRL, int RM>
__device__ __forceinline__ int dppi(int v) {
  return __builtin_amdgcn_update_dpp(v, v, CTRL, RM, 0xf, false);
}

template <int CTRL, int RM>
__device__ __forceinline__ double dpp_keymax(double k) {
  long long i = __double_as_longlong(k);
  int lo = (int)(unsigned)((unsigned long long)i & 0xffffffffull);
  int hi = (int)(unsigned)((unsigned long long)i >> 32);
  int plo = dppi<CTRL, RM>(lo);
  int phi = dppi<CTRL, RM>(hi);
  double o = __longlong_as_double(
      (long long)(((unsigned long long)(unsigned)phi << 32) | (unsigned)plo));
  return fmax(k, o);
}

__device__ __forceinline__ double wave_keymax(double k) {
  k = dpp_keymax<0x111, 0xf>(k);   // row_shr:1
  k = dpp_keymax<0x112, 0xf>(k);   // row_shr:2
  k = dpp_keymax<0x114, 0xf>(k);   // row_shr:4
  k = dpp_keymax<0x118, 0xf>(k);   // row_shr:8
  k = dpp_keymax<0x142, 0xa>(k);   // row_bcast:15
  k = dpp_keymax<0x143, 0xc>(k);   // row_bcast:31 -> lane 63 has result
  return k;
}

template <int C>
__device__ __forceinline__ float dppq(float v) {
  return __int_as_float(__builtin_amdgcn_update_dpp(
      __float_as_int(v), __float_as_int(v), C, 0xf, 0xf, false));
}

// ===========================================================================
// FPS role (blocks 0..7): r7 structure (8 waves x 8 slots, f64-key reduce)
// + packed-FP32 distance math (f32x2 -> v_pk_add/mul_f32, IEEE rn per half,
// contract(off) => bit-identical to the scalar __f*_rn sequence)
// + batched 8-wide publish (store drain off the barrier's vmcnt(0) path).
// ===========================================================================
__device__ void fps_role(const float* __restrict__ xyz,
                         float* __restrict__ out_newxyz,
                         int* __restrict__ ws_idx, char* smem)
{
#pragma clang fp contract(off)
  const int b    = blockIdx.x;
  const int t    = threadIdx.x;
  const int lane = t & 63;
  const int wave = t >> 6;

  float* sxyz4 = (float*)smem;                       // 64 KB padded xyz
  double (*swk)[FPS_W] = (double(*)[FPS_W])(smem + NPTS * 16);  // [2][8]

  const float* xb = xyz + (size_t)b * NPTS * 3;
  for (int p = t; p < NPTS; p += FPS_T) {
    sxyz4[p * 4 + 0] = xb[p * 3 + 0];
    sxyz4[p * 4 + 1] = xb[p * 3 + 1];
    sxyz4[p * 4 + 2] = xb[p * 3 + 2];
    sxyz4[p * 4 + 3] = 0.0f;
  }
  __syncthreads();

  f32x2 px[4], py[4], pz[4], dst[4];   // slot pairs (2k, 2k+1)
  unsigned iln[8];
#pragma unroll
  for (int j = 0; j < 4; ++j) {
    const int p0 = t + ((2 * j) << 9);
    const int p1 = t + ((2 * j + 1) << 9);
    px[j] = (f32x2){sxyz4[p0 * 4 + 0], sxyz4[p1 * 4 + 0]};
    py[j] = (f32x2){sxyz4[p0 * 4 + 1], sxyz4[p1 * 4 + 1]};
    pz[j] = (f32x2){sxyz4[p0 * 4 + 2], sxyz4[p1 * 4 + 2]};
    dst[j] = (f32x2){1e10f, 1e10f};    // matches reference init 1e10
    iln[2 * j]     = ~(unsigned)p0;    // tie-break: lowest original index
    iln[2 * j + 1] = ~(unsigned)p1;
  }

  int farh0 = 0, farh1 = 0;            // newxyz history in registers
  int fkeep = 0;                       // wave0 publish FIFO (1 word/lane)
  int far = 0;                         // reference: farthest starts at 0

  for (int n = 0; n < NQ; ++n) {
    const float4 c = *(const float4*)(sxyz4 + far * 4);   // broadcast b128
    if (wave == 0 && lane == (n & 7)) fkeep = far;
    if ((n & (FPS_T - 1)) == t) {
      if (n >> 9) farh1 = far; else farh0 = far;
    }

    const f32x2 cx2 = {c.x, c.x}, cy2 = {c.y, c.y}, cz2 = {c.z, c.z};
    double kk[8];
#pragma unroll
    for (int j = 0; j < 4; ++j) {
      // packed math, contract(off): per-half = sub,sub,sub,mul,mul,mul,
      // add(xx,yy), add(.,zz) in EXACT reference order/rounding
      f32x2 dx = px[j] - cx2;
      f32x2 dy = py[j] - cy2;
      f32x2 dz = pz[j] - cz2;
      f32x2 s  = (dx * dx + dy * dy) + dz * dz;
      f32x2 d  = dst[j];
      d.x = fminf(d.x, s.x);
      d.y = fminf(d.y, s.y);
      dst[j] = d;
      kk[2 * j] = __longlong_as_double((long long)(
          ((unsigned long long)__float_as_uint(d.x) << 32) | iln[2 * j]));
      kk[2 * j + 1] = __longlong_as_double((long long)(
          ((unsigned long long)__float_as_uint(d.y) << 32) | iln[2 * j + 1]));
    }
    double m0 = fmax(kk[0], kk[1]);
    double m1 = fmax(kk[2], kk[3]);
    double m2 = fmax(kk[4], kk[5]);
    double m3 = fmax(kk[6], kk[7]);
    double best = fmax(fmax(m0, m1), fmax(m2, m3));
    best = wave_keymax(best);          // lane 63 has wave max

    long long bi = __double_as_longlong(best);
    unsigned blo = (unsigned)__builtin_amdgcn_readlane(
        (int)(unsigned)((unsigned long long)bi & 0xffffffffull), 63);
    unsigned bhi = (unsigned)__builtin_amdgcn_readlane(
        (int)(unsigned)((unsigned long long)bi >> 32), 63);
    double wkey = __longlong_as_double(
        (long long)(((unsigned long long)bhi << 32) | blo));

    const int par = n & 1;             // double-buffered slots
    if (lane == 0) swk[par][wave] = wkey;
    __syncthreads();

    const double2* sp = (const double2*)swk[par];
    double2 a0 = sp[0], a1 = sp[1], a2 = sp[2], a3 = sp[3];
    double mk = fmax(fmax(fmax(a0.x, a0.y), fmax(a1.x, a1.y)),
                     fmax(fmax(a2.x, a2.y), fmax(a3.x, a3.y)));
    far = (int)(~(unsigned)((unsigned long long)__double_as_longlong(mk)));

    // batched publish: 8 indices, drain lands a full iteration before the
    // next barrier's vmcnt(0) -> off the critical path
    if (wave == 0 && lane < 8 && (n & 7) == 7)
      __hip_atomic_store(ws_idx + (b << 10) + (n & ~7) + lane, fkeep,
                         __ATOMIC_RELAXED, __HIP_MEMORY_SCOPE_AGENT);
  }

  // write all 1024 centroids once (bit-exact copies of input rows)
  {
    float4 c0 = *(const float4*)(sxyz4 + farh0 * 4);
    float* o0 = out_newxyz + ((size_t)b * NQ + t) * 3;
    o0[0] = c0.x; o0[1] = c0.y; o0[2] = c0.z;
    float4 c1 = *(const float4*)(sxyz4 + farh1 * 4);
    float* o1 = out_newxyz + ((size_t)b * NQ + FPS_T + t) * 3;
    o1[0] = c1.x; o1[1] = c1.y; o1[2] = c1.z;
  }
}

// ===========================================================================
// SA per-query machinery (unchanged from r7 — known correct)
// ===========================================================================
__device__ __forceinline__ void mlp_acc(float* __restrict__ acc,
                                        const float* __restrict__ XTb,
                                        const float* __restrict__ wg,
                                        int ldw, int nk, int fg, int sg)
{
#pragma unroll
  for (int i = 0; i < 32; ++i) acc[i] = 0.0f;
  const float* xrow = XTb + sg * 4;
  const float* wrow = wg + fg * 8;
#pragma unroll 4
  for (int k = 0; k < nk; ++k) {
    const float4 x  = *(const float4*)(xrow + k * XTW);
    const float4 wa = *(const float4*)(wrow + (size_t)k * ldw);
    const float4 wb = *(const float4*)(wrow + (size_t)k * ldw + 4);
    acc[0]  = fmaf(wa.x, x.x, acc[0]);  acc[1]  = fmaf(wa.x, x.y, acc[1]);
    acc[2]  = fmaf(wa.x, x.z, acc[2]);  acc[3]  = fmaf(wa.x, x.w, acc[3]);
    acc[4]  = fmaf(wa.y, x.x, acc[4]);  acc[5]  = fmaf(wa.y, x.y, acc[5]);
    acc[6]  = fmaf(wa.y, x.z, acc[6]);  acc[7]  = fmaf(wa.y, x.w, acc[7]);
    acc[8]  = fmaf(wa.z, x.x, acc[8]);  acc[9]  = fmaf(wa.z, x.y, acc[9]);
    acc[10] = fmaf(wa.z, x.z, acc[10]); acc[11] = fmaf(wa.z, x.w, acc[11]);
    acc[12] = fmaf(wa.w, x.x, acc[12]); acc[13] = fmaf(wa.w, x.y, acc[13]);
    acc[14] = fmaf(wa.w, x.z, acc[14]); acc[15] = fmaf(wa.w, x.w, acc[15]);
    acc[16] = fmaf(wb.x, x.x, acc[16]); acc[17] = fmaf(wb.x, x.y, acc[17]);
    acc[18] = fmaf(wb.x, x.z, acc[18]); acc[19] = fmaf(wb.x, x.w, acc[19]);
    acc[20] = fmaf(wb.y, x.x, acc[20]); acc[21] = fmaf(wb.y, x.y, acc[21]);
    acc[22] = fmaf(wb.y, x.z, acc[22]); acc[23] = fmaf(wb.y, x.w, acc[23]);
    acc[24] = fmaf(wb.z, x.x, acc[24]); acc[25] = fmaf(wb.z, x.y, acc[25]);
    acc[26] = fmaf(wb.z, x.z, acc[26]); acc[27] = fmaf(wb.z, x.w, acc[27]);
    acc[28] = fmaf(wb.w, x.x, acc[28]); acc[29] = fmaf(wb.w, x.y, acc[29]);
    acc[30] = fmaf(wb.w, x.z, acc[30]); acc[31] = fmaf(wb.w, x.w, acc[31]);
  }
}

__device__ __forceinline__ void store_layer(const float* __restrict__ acc,
                                            float* __restrict__ XTb,
                                            const float* __restrict__ g,
                                            const float* __restrict__ bi,
                                            const float* __restrict__ be,
                                            int fg, int sg, float RSQ)
{
  const float4 ga = *(const float4*)(g  + fg * 8);
  const float4 gb = *(const float4*)(g  + fg * 8 + 4);
  const float4 ba = *(const float4*)(bi + fg * 8);
  const float4 bb = *(const float4*)(bi + fg * 8 + 4);
  const float4 ea = *(const float4*)(be + fg * 8);
  const float4 eb = *(const float4*)(be + fg * 8 + 4);
  float sv[8] = {ga.x * RSQ, ga.y * RSQ, ga.z * RSQ, ga.w * RSQ,
                 gb.x * RSQ, gb.y * RSQ, gb.z * RSQ, gb.w * RSQ};
  float bv[8] = {ba.x, ba.y, ba.z, ba.w, bb.x, bb.y, bb.z, bb.w};
  float ev[8] = {ea.x, ea.y, ea.z, ea.w, eb.x, eb.y, eb.z, eb.w};
#pragma unroll
  for (int j = 0; j < 8; ++j) {
    float tv = fmaf(bv[j], sv[j], ev[j]);
    float4 h;
    h.x = fmaxf(fmaf(acc[j * 4 + 0], sv[j], tv), 0.0f);
    h.y = fmaxf(fmaf(acc[j * 4 + 1], sv[j], tv), 0.0f);
    h.z = fmaxf(fmaf(acc[j * 4 + 2], sv[j], tv), 0.0f);
    h.w = fmaxf(fmaf(acc[j * 4 + 3], sv[j], tv), 0.0f);
    *(float4*)(XTb + (fg * 8 + j) * XTW + sg * 4) = h;
  }
}

__device__ void worker_query(int q, int idx,
    const float* __restrict__ xyz, const float* __restrict__ pts,
    const float* __restrict__ w0, const float* __restrict__ b0,
    const float* __restrict__ g0, const float* __restrict__ be0,
    const float* __restrict__ w1, const float* __restrict__ b1,
    const float* __restrict__ g1, const float* __restrict__ be1,
    const float* __restrict__ w2, const float* __restrict__ b2,
    const float* __restrict__ g2, const float* __restrict__ be2,
    float* __restrict__ outp, float* __restrict__ XT, int* __restrict__ bidx,
    int lane)
{
  const int b = q >> 10;
  const float* xb = xyz + (size_t)b * NPTS * 3;
  // centroid from the immutable input via the published index: bit-identical
  // to newxyz[q], immune to cache staleness (xyz never written on GPU).
  const float cx = xb[idx * 3 + 0];
  const float cy = xb[idx * 3 + 1];
  const float cz = xb[idx * 3 + 2];

  // ---- ball query (pipelined 2 ahead): first <=32 in-radius, ascending ----
  int cnt = 0;
  float x0 = xb[lane * 3 + 0], y0 = xb[lane * 3 + 1], z0 = xb[lane * 3 + 2];
  float x1 = xb[(64 + lane) * 3 + 0], y1 = xb[(64 + lane) * 3 + 1],
        z1 = xb[(64 + lane) * 3 + 2];
  for (int ch = 0; ch < 64; ++ch) {
    const int an = (min(ch + 2, 63) << 6) | lane;
    float nx = xb[an * 3 + 0], ny = xb[an * 3 + 1], nz = xb[an * 3 + 2];
    float dx = __fsub_rn(cx, x0);
    float dy = __fsub_rn(cy, y0);
    float dz = __fsub_rn(cz, z0);
    float d2 = __fadd_rn(__fadd_rn(__fmul_rn(dx, dx), __fmul_rn(dy, dy)),
                         __fmul_rn(dz, dz));
    bool in = d2 < 0.04f;
    unsigned long long bal = __ballot(in);
    int pos = cnt + (int)__popcll(bal & ((1ull << lane) - 1ull));
    if (in && pos < 32) bidx[pos] = (ch << 6) | lane;
    cnt += (int)__popcll(bal);
    x0 = x1; y0 = y1; z0 = z1;
    x1 = nx; y1 = ny; z1 = nz;
    if (cnt >= 32) break;
  }
  if (cnt > 32) cnt = 32;
  int i0 = bidx[0];
  if (lane < 32 && lane >= cnt) bidx[lane] = i0;
  __builtin_amdgcn_wave_barrier();

  // ---- gather into X^T[k][s] ----
  const int s  = lane & 31;
  const int kc = lane >> 5;
  const int is = bidx[s];
  const float4* pr4 = (const float4*)(pts + ((size_t)(b * NPTS + is)) * 64 + kc * 32);
  float* xcol = XT + s;
#pragma unroll
  for (int c = 0; c < 8; ++c) {
    float4 v = pr4[c];
    xcol[(kc * 32 + c * 4 + 0) * XTW] = v.x;
    xcol[(kc * 32 + c * 4 + 1) * XTW] = v.y;
    xcol[(kc * 32 + c * 4 + 2) * XTW] = v.z;
    xcol[(kc * 32 + c * 4 + 3) * XTW] = v.w;
  }
  if (kc == 0) {
    float ax = xb[is * 3 + 0], ay = xb[is * 3 + 1], az = xb[is * 3 + 2];
    xcol[64 * XTW] = ax - cx;
    xcol[65 * XTW] = ay - cy;
    xcol[66 * XTW] = az - cz;
  }
  __builtin_amdgcn_wave_barrier();

  const int fg = lane >> 3;
  const int sg = lane & 7;
  const float RSQ = rsqrtf(1.0f + 0.001f);
  float acc[32];

  mlp_acc(acc, XT, w0, 64, 67, fg, sg);
  store_layer(acc, XT, g0, b0, be0, fg, sg, RSQ);
  __builtin_amdgcn_wave_barrier();

  mlp_acc(acc, XT, w1, 64, 64, fg, sg);
  store_layer(acc, XT, g1, b1, be1, fg, sg, RSQ);
  __builtin_amdgcn_wave_barrier();

#pragma unroll
  for (int pass = 0; pass < 2; ++pass) {
    const int fofs = pass << 6;
    mlp_acc(acc, XT, w2 + fofs, 128, 64, fg, sg);
    const float4 ga = *(const float4*)(g2  + fofs + fg * 8);
    const float4 gb = *(const float4*)(g2  + fofs + fg * 8 + 4);
    const float4 ba = *(const float4*)(b2  + fofs + fg * 8);
    const float4 bb = *(const float4*)(b2  + fofs + fg * 8 + 4);
    const float4 ea = *(const float4*)(be2 + fofs + fg * 8);
    const float4 eb = *(const float4*)(be2 + fofs + fg * 8 + 4);
    float sv[8] = {ga.x * RSQ, ga.y * RSQ, ga.z * RSQ, ga.w * RSQ,
                   gb.x * RSQ, gb.y * RSQ, gb.z * RSQ, gb.w * RSQ};
    float bv[8] = {ba.x, ba.y, ba.z, ba.w, bb.x, bb.y, bb.z, bb.w};
    float ev[8] = {ea.x, ea.y, ea.z, ea.w, eb.x, eb.y, eb.z, eb.w};
    float r[8];
#pragma unroll
    for (int j = 0; j < 8; ++j) {
      float mx = fmaxf(fmaxf(acc[j * 4 + 0], acc[j * 4 + 1]),
                       fmaxf(acc[j * 4 + 2], acc[j * 4 + 3]));
      float mn = fminf(fminf(acc[j * 4 + 0], acc[j * 4 + 1]),
                       fminf(acc[j * 4 + 2], acc[j * 4 + 3]));
      mx = fmaxf(mx, dppq<0xB1>(mx));
      mx = fmaxf(mx, dppq<0x4E>(mx));
      mx = fmaxf(mx, dppq<0x141>(mx));
      mn = fminf(mn, dppq<0xB1>(mn));
      mn = fminf(mn, dppq<0x4E>(mn));
      mn = fminf(mn, dppq<0x141>(mn));
      float tv = fmaf(bv[j], sv[j], ev[j]);
      float m  = (sv[j] >= 0.0f) ? mx : mn;    // maxpool commutes with affine
      r[j] = fmaxf(fmaf(sv[j], m, tv), 0.0f);
    }
    if (sg == 0) {
      float* o = outp + (size_t)q * 128 + fofs + fg * 8;
      *(float4*)(o)     = make_float4(r[0], r[1], r[2], r[3]);
      *(float4*)(o + 4) = make_float4(r[4], r[5], r[6], r[7]);
    }
  }
}

// ===========================================================================
// Fused kernel: 248 blocks x 512 thr, 84 KB LDS => 1 block/CU => all blocks
// co-resident regardless of dispatch order (deadlock-impossible).  Blocks
// 0..7: FPS.  Blocks 8..247: 8 persistent worker waves; spin (s_sleep,
// bounded) on the published index then run ball-query+MLP.
// ===========================================================================
__global__ __launch_bounds__(FPS_T, 1) void fused_kernel(
    const float* __restrict__ xyz, const float* __restrict__ pts,
    const float* __restrict__ w0, const float* __restrict__ b0,
    const float* __restrict__ g0, const float* __restrict__ be0,
    const float* __restrict__ w1, const float* __restrict__ b1,
    const float* __restrict__ g1, const float* __restrict__ be1,
    const float* __restrict__ w2, const float* __restrict__ b2,
    const float* __restrict__ g2, const float* __restrict__ be2,
    float* __restrict__ newxyz, float* __restrict__ newpts,
    int* __restrict__ ws_idx)
{
  __shared__ __align__(16) char smem[SMEM_BYTES];

  if (blockIdx.x < FPS_NB) {
    fps_role(xyz, newxyz, ws_idx, smem);
    return;
  }

  const int lane = threadIdx.x & 63;
  const int wave = threadIdx.x >> 6;
  char* sl = smem + wave * WSLICE;
  float* XT  = (float*)sl;           // 67*36*4 = 9648 B
  int* bidx  = (int*)(sl + 9648);    // 128 B

  const int W = (blockIdx.x - FPS_NB) * 8 + wave;
  for (int g = W; g < NB * NQ; g += NWRK) {
    const int b = g & 7;
    const int n = g >> 3;
    const int q = (b << 10) | n;

    const int* slot = ws_idx + q;
    int idx = __hip_atomic_load(slot, __ATOMIC_RELAXED, __HIP_MEMORY_SCOPE_AGENT);
    int spins = 0;
    while ((unsigned)idx >= (unsigned)NPTS) {       // sentinel/poison = wait
      __builtin_amdgcn_s_sleep(16);
      idx = __hip_atomic_load(slot, __ATOMIC_RELAXED, __HIP_MEMORY_SCOPE_AGENT);
      if (++spins > 32768) { idx &= (NPTS - 1); break; }  // bounded: no hang
    }

    worker_query(q, idx, xyz, pts, w0, b0, g0, be0, w1, b1, g1, be1,
                 w2, b2, g2, be2, newpts, XT, bidx, lane);
  }
}

// ===========================================================================
extern "C" void kernel_launch(void* const* d_in, const int* in_sizes, int n_in,
                              void* d_out, int out_size, void* d_ws, size_t ws_size,
                              hipStream_t stream)
{
  const float* xyz = (const float*)d_in[0];
  const float* pts = (const float*)d_in[1];
  const float* w0  = (const float*)d_in[2];
  const float* b0  = (const float*)d_in[3];
  const float* g0  = (const float*)d_in[4];
  const float* be0 = (const float*)d_in[5];
  const float* w1  = (const float*)d_in[6];
  const float* b1  = (const float*)d_in[7];
  const float* g1  = (const float*)d_in[8];
  const float* be1 = (const float*)d_in[9];
  const float* w2  = (const float*)d_in[10];
  const float* b2  = (const float*)d_in[11];
  const float* g2  = (const float*)d_in[12];
  const float* be2 = (const float*)d_in[13];

  float* out    = (float*)d_out;
  float* newxyz = out;                    // 8*1024*3
  float* newpts = out + NB * NQ * 3;      // 8*1024*128
  int*   ws_idx = (int*)d_ws;             // 8192 published indices

  // sentinel-fill the mailbox (0xAA... is an invalid index)
  hipMemsetAsync(d_ws, 0xAA, (size_t)NB * NQ * sizeof(int), stream);

  hipLaunchKernelGGL(fused_kernel, dim3(FPS_NB + WRK_NB), dim3(FPS_T), 0, stream,
                     xyz, pts, w0, b0, g0, be0, w1, b1, g1, be1,
                     w2, b2, g2, be2, newxyz, newpts, ws_idx);
}

// Round 10
// 696.047 us; speedup vs baseline: 1.1521x; 1.0574x over previous
//
#include <hip/hip_runtime.h>

#define NPTS 4096
#define NQ   1024
#define NB   8
#define XTW  36            // sa LDS row stride (floats): 144B = 9*16B

#define FPS_T  512
#define FPS_W  8               // 8 working waves (2/SIMD — latency hiding)
#define PPT    8               // points per thread
#define FPS_NB 8               // fps blocks (one per batch)
#define WRK_NB 240             // persistent worker blocks
#define NWRK   (WRK_NB * 8)    // 1920 worker waves
#define WSLICE 10496           // per-wave worker LDS slice (>= 9648 XT + 128 bidx)
#define SMEM_BYTES (WSLICE * 8) // 83968 B: 2x > 160KiB => exactly 1 block/CU

// ===========================================================================
// DPP + f64-key helpers (r7-proven).  FPS keys: (dst_bits<<32)|~idx, sign
// bit always 0; v_max_f64 == u64 max here (hi word is an f32 bit pattern in
// [0,1e10] => never NaN; denormal-f64 keys only for dst==0 = already-selected
// points which can never win).  Unique idx => no ties.  Bit-exact argmax,
// lowest-original-index tie-break.
// ===========================================================================
template <int CTRL, int RM>
__device__ __forceinline__ int dppi(int v) {
  return __builtin_amdgcn_update_dpp(v, v, CTRL, RM, 0xf, false);
}

template <int CTRL, int RM>
__device__ __forceinline__ double dpp_keymax(double k) {
  long long i = __double_as_longlong(k);
  int lo = (int)(unsigned)((unsigned long long)i & 0xffffffffull);
  int hi = (int)(unsigned)((unsigned long long)i >> 32);
  int plo = dppi<CTRL, RM>(lo);
  int phi = dppi<CTRL, RM>(hi);
  double o = __longlong_as_double(
      (long long)(((unsigned long long)(unsigned)phi << 32) | (unsigned)plo));
  return fmax(k, o);
}

__device__ __forceinline__ double wave_keymax(double k) {
  k = dpp_keymax<0x111, 0xf>(k);   // row_shr:1
  k = dpp_keymax<0x112, 0xf>(k);   // row_shr:2
  k = dpp_keymax<0x114, 0xf>(k);   // row_shr:4
  k = dpp_keymax<0x118, 0xf>(k);   // row_shr:8
  k = dpp_keymax<0x142, 0xa>(k);   // row_bcast:15
  k = dpp_keymax<0x143, 0xc>(k);   // row_bcast:31 -> lane 63 has result
  return k;
}

template <int C>
__device__ __forceinline__ float dppq(float v) {
  return __int_as_float(__builtin_amdgcn_update_dpp(
      __float_as_int(v), __float_as_int(v), C, 0xf, 0xf, false));
}

// ===========================================================================
// FPS role (blocks 0..7): exact r7 inner loop (scalar __f*_rn math — CDNA4
// has NO packed-fp32 rate doubling, r9 lesson) with three serial-chain
// shaves: lane-63 direct LDS key write (no readlane round-trip), batched
// 8-wide publish (store drain off 7/8 barriers), no in-loop newxyz history
// (workers write newxyz from the published index).
// ===========================================================================
__device__ void fps_role(const float* __restrict__ xyz,
                         int* __restrict__ ws_idx, char* smem)
{
  const int b    = blockIdx.x;
  const int t    = threadIdx.x;
  const int lane = t & 63;
  const int wave = t >> 6;

  float* sxyz4 = (float*)smem;                       // 64 KB padded xyz
  double (*swk)[FPS_W] = (double(*)[FPS_W])(smem + NPTS * 16);  // [2][8]

  const float* xb = xyz + (size_t)b * NPTS * 3;
  for (int p = t; p < NPTS; p += FPS_T) {
    sxyz4[p * 4 + 0] = xb[p * 3 + 0];
    sxyz4[p * 4 + 1] = xb[p * 3 + 1];
    sxyz4[p * 4 + 2] = xb[p * 3 + 2];
    sxyz4[p * 4 + 3] = 0.0f;
  }
  __syncthreads();

  float px[PPT], py[PPT], pz[PPT], dst[PPT];
  unsigned ilo[PPT];
#pragma unroll
  for (int k = 0; k < PPT; ++k) {
    int p = t + (k << 9);
    px[k] = sxyz4[p * 4 + 0];
    py[k] = sxyz4[p * 4 + 1];
    pz[k] = sxyz4[p * 4 + 2];
    dst[k] = 1e10f;                    // matches reference init 1e10
    ilo[k] = ~(unsigned)p;             // tie-break: lowest original index
  }

  int fkeep = 0;                       // wave0 publish FIFO (1 word/lane)
  int far = 0;                         // reference: farthest starts at 0

  for (int n = 0; n < NQ; ++n) {
    const float4 c = *(const float4*)(sxyz4 + far * 4);   // broadcast b128
    if (wave == 0 && lane == (n & 7)) fkeep = far;

    double kk[PPT];
#pragma unroll
    for (int k = 0; k < PPT; ++k) {
      // EXACT reference order: (dx*dx + dy*dy) + dz*dz, no FMA contraction
      float dx = __fsub_rn(px[k], c.x);
      float dy = __fsub_rn(py[k], c.y);
      float dz = __fsub_rn(pz[k], c.z);
      float d2 = __fadd_rn(__fadd_rn(__fmul_rn(dx, dx), __fmul_rn(dy, dy)),
                           __fmul_rn(dz, dz));
      float dm = fminf(dst[k], d2);
      dst[k] = dm;
      kk[k] = __longlong_as_double((long long)(
          ((unsigned long long)__float_as_uint(dm) << 32) | ilo[k]));
    }
    double m0 = fmax(kk[0], kk[1]);
    double m1 = fmax(kk[2], kk[3]);
    double m2 = fmax(kk[4], kk[5]);
    double m3 = fmax(kk[6], kk[7]);
    double best = fmax(fmax(m0, m1), fmax(m2, m3));
    best = wave_keymax(best);          // lane 63 has wave max

    // lane 63 writes its key directly — no readlane/rebuild round-trip
    const int par = n & 1;             // double-buffered slots
    if (lane == 63) swk[par][wave] = best;
    __syncthreads();

    const double2* sp = (const double2*)swk[par];
    double2 a0 = sp[0], a1 = sp[1], a2 = sp[2], a3 = sp[3];
    double mk = fmax(fmax(fmax(a0.x, a0.y), fmax(a1.x, a1.y)),
                     fmax(fmax(a2.x, a2.y), fmax(a3.x, a3.y)));
    far = (int)(~(unsigned)((unsigned long long)__double_as_longlong(mk)));

    // batched publish: 8 indices every 8th iter — the store has a full
    // iteration to retire before the next barrier's vmcnt(0) drain
    if (wave == 0 && lane < 8 && (n & 7) == 7)
      __hip_atomic_store(ws_idx + (b << 10) + (n & ~7) + lane, fkeep,
                         __ATOMIC_RELAXED, __HIP_MEMORY_SCOPE_AGENT);
  }
}

// ===========================================================================
// SA per-query machinery (unchanged from r7 — known correct) + newxyz write
// ===========================================================================
__device__ __forceinline__ void mlp_acc(float* __restrict__ acc,
                                        const float* __restrict__ XTb,
                                        const float* __restrict__ wg,
                                        int ldw, int nk, int fg, int sg)
{
#pragma unroll
  for (int i = 0; i < 32; ++i) acc[i] = 0.0f;
  const float* xrow = XTb + sg * 4;
  const float* wrow = wg + fg * 8;
#pragma unroll 4
  for (int k = 0; k < nk; ++k) {
    const float4 x  = *(const float4*)(xrow + k * XTW);
    const float4 wa = *(const float4*)(wrow + (size_t)k * ldw);
    const float4 wb = *(const float4*)(wrow + (size_t)k * ldw + 4);
    acc[0]  = fmaf(wa.x, x.x, acc[0]);  acc[1]  = fmaf(wa.x, x.y, acc[1]);
    acc[2]  = fmaf(wa.x, x.z, acc[2]);  acc[3]  = fmaf(wa.x, x.w, acc[3]);
    acc[4]  = fmaf(wa.y, x.x, acc[4]);  acc[5]  = fmaf(wa.y, x.y, acc[5]);
    acc[6]  = fmaf(wa.y, x.z, acc[6]);  acc[7]  = fmaf(wa.y, x.w, acc[7]);
    acc[8]  = fmaf(wa.z, x.x, acc[8]);  acc[9]  = fmaf(wa.z, x.y, acc[9]);
    acc[10] = fmaf(wa.z, x.z, acc[10]); acc[11] = fmaf(wa.z, x.w, acc[11]);
    acc[12] = fmaf(wa.w, x.x, acc[12]); acc[13] = fmaf(wa.w, x.y, acc[13]);
    acc[14] = fmaf(wa.w, x.z, acc[14]); acc[15] = fmaf(wa.w, x.w, acc[15]);
    acc[16] = fmaf(wb.x, x.x, acc[16]); acc[17] = fmaf(wb.x, x.y, acc[17]);
    acc[18] = fmaf(wb.x, x.z, acc[18]); acc[19] = fmaf(wb.x, x.w, acc[19]);
    acc[20] = fmaf(wb.y, x.x, acc[20]); acc[21] = fmaf(wb.y, x.y, acc[21]);
    acc[22] = fmaf(wb.y, x.z, acc[22]); acc[23] = fmaf(wb.y, x.w, acc[23]);
    acc[24] = fmaf(wb.z, x.x, acc[24]); acc[25] = fmaf(wb.z, x.y, acc[25]);
    acc[26] = fmaf(wb.z, x.z, acc[26]); acc[27] = fmaf(wb.z, x.w, acc[27]);
    acc[28] = fmaf(wb.w, x.x, acc[28]); acc[29] = fmaf(wb.w, x.y, acc[29]);
    acc[30] = fmaf(wb.w, x.z, acc[30]); acc[31] = fmaf(wb.w, x.w, acc[31]);
  }
}

__device__ __forceinline__ void store_layer(const float* __restrict__ acc,
                                            float* __restrict__ XTb,
                                            const float* __restrict__ g,
                                            const float* __restrict__ bi,
                                            const float* __restrict__ be,
                                            int fg, int sg, float RSQ)
{
  const float4 ga = *(const float4*)(g  + fg * 8);
  const float4 gb = *(const float4*)(g  + fg * 8 + 4);
  const float4 ba = *(const float4*)(bi + fg * 8);
  const float4 bb = *(const float4*)(bi + fg * 8 + 4);
  const float4 ea = *(const float4*)(be + fg * 8);
  const float4 eb = *(const float4*)(be + fg * 8 + 4);
  float sv[8] = {ga.x * RSQ, ga.y * RSQ, ga.z * RSQ, ga.w * RSQ,
                 gb.x * RSQ, gb.y * RSQ, gb.z * RSQ, gb.w * RSQ};
  float bv[8] = {ba.x, ba.y, ba.z, ba.w, bb.x, bb.y, bb.z, bb.w};
  float ev[8] = {ea.x, ea.y, ea.z, ea.w, eb.x, eb.y, eb.z, eb.w};
#pragma unroll
  for (int j = 0; j < 8; ++j) {
    float tv = fmaf(bv[j], sv[j], ev[j]);
    float4 h;
    h.x = fmaxf(fmaf(acc[j * 4 + 0], sv[j], tv), 0.0f);
    h.y = fmaxf(fmaf(acc[j * 4 + 1], sv[j], tv), 0.0f);
    h.z = fmaxf(fmaf(acc[j * 4 + 2], sv[j], tv), 0.0f);
    h.w = fmaxf(fmaf(acc[j * 4 + 3], sv[j], tv), 0.0f);
    *(float4*)(XTb + (fg * 8 + j) * XTW + sg * 4) = h;
  }
}

__device__ void worker_query(int q, int idx,
    const float* __restrict__ xyz, const float* __restrict__ pts,
    const float* __restrict__ w0, const float* __restrict__ b0,
    const float* __restrict__ g0, const float* __restrict__ be0,
    const float* __restrict__ w1, const float* __restrict__ b1,
    const float* __restrict__ g1, const float* __restrict__ be1,
    const float* __restrict__ w2, const float* __restrict__ b2,
    const float* __restrict__ g2, const float* __restrict__ be2,
    float* __restrict__ newxyz, float* __restrict__ outp,
    float* __restrict__ XT, int* __restrict__ bidx, int lane)
{
  const int b = q >> 10;
  const float* xb = xyz + (size_t)b * NPTS * 3;
  // centroid from the immutable input via the published index: bit-identical
  // to the reference's newxyz[q] (exact copy of an input row).
  const float cx = xb[idx * 3 + 0];
  const float cy = xb[idx * 3 + 1];
  const float cz = xb[idx * 3 + 2];
  if (lane == 0) {                     // workers own the newxyz output now
    float* o = newxyz + (size_t)q * 3;
    o[0] = cx; o[1] = cy; o[2] = cz;
  }

  // ---- ball query (pipelined 2 ahead): first <=32 in-radius, ascending ----
  int cnt = 0;
  float x0 = xb[lane * 3 + 0], y0 = xb[lane * 3 + 1], z0 = xb[lane * 3 + 2];
  float x1 = xb[(64 + lane) * 3 + 0], y1 = xb[(64 + lane) * 3 + 1],
        z1 = xb[(64 + lane) * 3 + 2];
  for (int ch = 0; ch < 64; ++ch) {
    const int an = (min(ch + 2, 63) << 6) | lane;
    float nx = xb[an * 3 + 0], ny = xb[an * 3 + 1], nz = xb[an * 3 + 2];
    float dx = __fsub_rn(cx, x0);
    float dy = __fsub_rn(cy, y0);
    float dz = __fsub_rn(cz, z0);
    float d2 = __fadd_rn(__fadd_rn(__fmul_rn(dx, dx), __fmul_rn(dy, dy)),
                         __fmul_rn(dz, dz));
    bool in = d2 < 0.04f;
    unsigned long long bal = __ballot(in);
    int pos = cnt + (int)__popcll(bal & ((1ull << lane) - 1ull));
    if (in && pos < 32) bidx[pos] = (ch << 6) | lane;
    cnt += (int)__popcll(bal);
    x0 = x1; y0 = y1; z0 = z1;
    x1 = nx; y1 = ny; z1 = nz;
    if (cnt >= 32) break;
  }
  if (cnt > 32) cnt = 32;
  int i0 = bidx[0];
  if (lane < 32 && lane >= cnt) bidx[lane] = i0;
  __builtin_amdgcn_wave_barrier();

  // ---- gather into X^T[k][s] ----
  const int s  = lane & 31;
  const int kc = lane >> 5;
  const int is = bidx[s];
  const float4* pr4 = (const float4*)(pts + ((size_t)(b * NPTS + is)) * 64 + kc * 32);
  float* xcol = XT + s;
#pragma unroll
  for (int c = 0; c < 8; ++c) {
    float4 v = pr4[c];
    xcol[(kc * 32 + c * 4 + 0) * XTW] = v.x;
    xcol[(kc * 32 + c * 4 + 1) * XTW] = v.y;
    xcol[(kc * 32 + c * 4 + 2) * XTW] = v.z;
    xcol[(kc * 32 + c * 4 + 3) * XTW] = v.w;
  }
  if (kc == 0) {
    float ax = xb[is * 3 + 0], ay = xb[is * 3 + 1], az = xb[is * 3 + 2];
    xcol[64 * XTW] = ax - cx;
    xcol[65 * XTW] = ay - cy;
    xcol[66 * XTW] = az - cz;
  }
  __builtin_amdgcn_wave_barrier();

  const int fg = lane >> 3;
  const int sg = lane & 7;
  const float RSQ = rsqrtf(1.0f + 0.001f);
  float acc[32];

  mlp_acc(acc, XT, w0, 64, 67, fg, sg);
  store_layer(acc, XT, g0, b0, be0, fg, sg, RSQ);
  __builtin_amdgcn_wave_barrier();

  mlp_acc(acc, XT, w1, 64, 64, fg, sg);
  store_layer(acc, XT, g1, b1, be1, fg, sg, RSQ);
  __builtin_amdgcn_wave_barrier();

#pragma unroll
  for (int pass = 0; pass < 2; ++pass) {
    const int fofs = pass << 6;
    mlp_acc(acc, XT, w2 + fofs, 128, 64, fg, sg);
    const float4 ga = *(const float4*)(g2  + fofs + fg * 8);
    const float4 gb = *(const float4*)(g2  + fofs + fg * 8 + 4);
    const float4 ba = *(const float4*)(b2  + fofs + fg * 8);
    const float4 bb = *(const float4*)(b2  + fofs + fg * 8 + 4);
    const float4 ea = *(const float4*)(be2 + fofs + fg * 8);
    const float4 eb = *(const float4*)(be2 + fofs + fg * 8 + 4);
    float sv[8] = {ga.x * RSQ, ga.y * RSQ, ga.z * RSQ, ga.w * RSQ,
                   gb.x * RSQ, gb.y * RSQ, gb.z * RSQ, gb.w * RSQ};
    float bv[8] = {ba.x, ba.y, ba.z, ba.w, bb.x, bb.y, bb.z, bb.w};
    float ev[8] = {ea.x, ea.y, ea.z, ea.w, eb.x, eb.y, eb.z, eb.w};
    float r[8];
#pragma unroll
    for (int j = 0; j < 8; ++j) {
      float mx = fmaxf(fmaxf(acc[j * 4 + 0], acc[j * 4 + 1]),
                       fmaxf(acc[j * 4 + 2], acc[j * 4 + 3]));
      float mn = fminf(fminf(acc[j * 4 + 0], acc[j * 4 + 1]),
                       fminf(acc[j * 4 + 2], acc[j * 4 + 3]));
      mx = fmaxf(mx, dppq<0xB1>(mx));
      mx = fmaxf(mx, dppq<0x4E>(mx));
      mx = fmaxf(mx, dppq<0x141>(mx));
      mn = fminf(mn, dppq<0xB1>(mn));
      mn = fminf(mn, dppq<0x4E>(mn));
      mn = fminf(mn, dppq<0x141>(mn));
      float tv = fmaf(bv[j], sv[j], ev[j]);
      float m  = (sv[j] >= 0.0f) ? mx : mn;    // maxpool commutes with affine
      r[j] = fmaxf(fmaf(sv[j], m, tv), 0.0f);
    }
    if (sg == 0) {
      float* o = outp + (size_t)q * 128 + fofs + fg * 8;
      *(float4*)(o)     = make_float4(r[0], r[1], r[2], r[3]);
      *(float4*)(o + 4) = make_float4(r[4], r[5], r[6], r[7]);
    }
  }
}

// ===========================================================================
// Fused kernel: 248 blocks x 512 thr, 84 KB LDS => 1 block/CU => all blocks
// co-resident regardless of dispatch order (deadlock-impossible).  Blocks
// 0..7: FPS.  Blocks 8..247: 8 persistent worker waves; spin (s_sleep,
// bounded) on the published index then run ball-query+MLP.
// ===========================================================================
__global__ __launch_bounds__(FPS_T, 1) void fused_kernel(
    const float* __restrict__ xyz, const float* __restrict__ pts,
    const float* __restrict__ w0, const float* __restrict__ b0,
    const float* __restrict__ g0, const float* __restrict__ be0,
    const float* __restrict__ w1, const float* __restrict__ b1,
    const float* __restrict__ g1, const float* __restrict__ be1,
    const float* __restrict__ w2, const float* __restrict__ b2,
    const float* __restrict__ g2, const float* __restrict__ be2,
    float* __restrict__ newxyz, float* __restrict__ newpts,
    int* __restrict__ ws_idx)
{
  __shared__ __align__(16) char smem[SMEM_BYTES];

  if (blockIdx.x < FPS_NB) {
    fps_role(xyz, ws_idx, smem);
    return;
  }

  const int lane = threadIdx.x & 63;
  const int wave = threadIdx.x >> 6;
  char* sl = smem + wave * WSLICE;
  float* XT  = (float*)sl;           // 67*36*4 = 9648 B
  int* bidx  = (int*)(sl + 9648);    // 128 B

  const int W = (blockIdx.x - FPS_NB) * 8 + wave;
  for (int g = W; g < NB * NQ; g += NWRK) {
    const int b = g & 7;
    const int n = g >> 3;
    const int q = (b << 10) | n;

    const int* slot = ws_idx + q;
    int idx = __hip_atomic_load(slot, __ATOMIC_RELAXED, __HIP_MEMORY_SCOPE_AGENT);
    int spins = 0;
    while ((unsigned)idx >= (unsigned)NPTS) {       // sentinel/poison = wait
      __builtin_amdgcn_s_sleep(16);
      idx = __hip_atomic_load(slot, __ATOMIC_RELAXED, __HIP_MEMORY_SCOPE_AGENT);
      if (++spins > 32768) { idx &= (NPTS - 1); break; }  // bounded: no hang
    }

    worker_query(q, idx, xyz, pts, w0, b0, g0, be0, w1, b1, g1, be1,
                 w2, b2, g2, be2, newxyz, newpts, XT, bidx, lane);
  }
}

// ===========================================================================
extern "C" void kernel_launch(void* const* d_in, const int* in_sizes, int n_in,
                              void* d_out, int out_size, void* d_ws, size_t ws_size,
                              hipStream_t stream)
{
  const float* xyz = (const float*)d_in[0];
  const float* pts = (const float*)d_in[1];
  const float* w0  = (const float*)d_in[2];
  const float* b0  = (const float*)d_in[3];
  const float* g0  = (const float*)d_in[4];
  const float* be0 = (const float*)d_in[5];
  const float* w1  = (const float*)d_in[6];
  const float* b1  = (const float*)d_in[7];
  const float* g1  = (const float*)d_in[8];
  const float* be1 = (const float*)d_in[9];
  const float* w2  = (const float*)d_in[10];
  const float* b2  = (const float*)d_in[11];
  const float* g2  = (const float*)d_in[12];
  const float* be2 = (const float*)d_in[13];

  float* out    = (float*)d_out;
  float* newxyz = out;                    // 8*1024*3
  float* newpts = out + NB * NQ * 3;      // 8*1024*128
  int*   ws_idx = (int*)d_ws;             // 8192 published indices

  // sentinel-fill the mailbox (0xAA... is an invalid index)
  hipMemsetAsync(d_ws, 0xAA, (size_t)NB * NQ * sizeof(int), stream);

  hipLaunchKernelGGL(fused_kernel, dim3(FPS_NB + WRK_NB), dim3(FPS_T), 0, stream,
                     xyz, pts, w0, b0, g0, be0, w1, b1, g1, be1,
                     w2, b2, g2, be2, newxyz, newpts, ws_idx);
}

// Round 13
// 666.397 us; speedup vs baseline: 1.2034x; 1.0445x over previous
//
#include <hip/hip_runtime.h>

#define NPTS 4096
#define NQ   1024
#define NB   8
#define XTW  36            // sa LDS row stride (floats): 144B = 9*16B

#define FPS_T  512
#define FPS_W  8               // waves per fps block
#define PPT    8               // points per thread in fps
#define FPS_NB 8               // fps blocks (one per batch)
#define WRK_NB 240             // persistent worker blocks
#define NWRK   (WRK_NB * 8)    // 1920 worker waves
#define WSLICE 10496           // per-wave worker LDS slice (>= 9648 XT + 128 bidx)
#define SMEM_BYTES (WSLICE * 8) // 83968 B: 2x83968 > 160KiB => exactly 1 block/CU

// ===========================================================================
// DPP + f64-key helpers.  FPS keys: (dst_bits<<32)|~idx, sign bit always 0.
// v_max_f64 == u64 max here: jax-uniform coords lie on a k*2^-24 grid, so any
// nonzero d2 >= 2^-48 => hi word is a comfortably-normal f32 => normal f64.
// The only denormal-f64 keys have dst==0 (already-selected points), which can
// never win while any dst>0 exists (>=3072 points) — DAZ cannot change the
// selection.  Equal keys impossible (unique idx).  Bit-exact argmax,
// lowest-original-index tie-break.
// ===========================================================================
template <int CTRL, int RM>
__device__ __forceinline__ int dppi(int v) {
  return __builtin_amdgcn_update_dpp(v, v, CTRL, RM, 0xf, false);
}

template <int CTRL, int RM>
__device__ __forceinline__ double dpp_keymax(double k) {
  long long i = __double_as_longlong(k);
  int lo = (int)(unsigned)((unsigned long long)i & 0xffffffffull);
  int hi = (int)(unsigned)((unsigned long long)i >> 32);
  int plo = dppi<CTRL, RM>(lo);
  int phi = dppi<CTRL, RM>(hi);
  double o = __longlong_as_double(
      (long long)(((unsigned long long)(unsigned)phi << 32) | (unsigned)plo));
  return fmax(k, o);
}

__device__ __forceinline__ double wave_keymax(double k) {
  k = dpp_keymax<0x111, 0xf>(k);   // row_shr:1
  k = dpp_keymax<0x112, 0xf>(k);   // row_shr:2
  k = dpp_keymax<0x114, 0xf>(k);   // row_shr:4
  k = dpp_keymax<0x118, 0xf>(k);   // row_shr:8
  k = dpp_keymax<0x142, 0xa>(k);   // row_bcast:15
  k = dpp_keymax<0x143, 0xc>(k);   // row_bcast:31 -> lane 63 has result
  return k;
}

template <int C>
__device__ __forceinline__ float dppq(float v) {
  return __int_as_float(__builtin_amdgcn_update_dpp(
      __float_as_int(v), __float_as_int(v), C, 0xf, 0xf, false));
}

// ===========================================================================
// FPS role (blocks 0..7): r6 dense structure + f64-key max.  Publishes the
// selected index per iteration via relaxed AGENT-scope atomic store (single
// word = payload; fire-and-forget, no fence on the critical path).
// ===========================================================================
__device__ void fps_role(const float* __restrict__ xyz,
                         float* __restrict__ out_newxyz,
                         int* __restrict__ ws_idx, char* smem)
{
  const int b    = blockIdx.x;
  const int t    = threadIdx.x;
  const int lane = t & 63;
  const int wave = t >> 6;

  float* sxyz4 = (float*)smem;                       // 64 KB padded xyz
  double (*swk)[FPS_W] = (double(*)[FPS_W])(smem + NPTS * 16);

  const float* xb = xyz + (size_t)b * NPTS * 3;
  for (int p = t; p < NPTS; p += FPS_T) {
    sxyz4[p * 4 + 0] = xb[p * 3 + 0];
    sxyz4[p * 4 + 1] = xb[p * 3 + 1];
    sxyz4[p * 4 + 2] = xb[p * 3 + 2];
    sxyz4[p * 4 + 3] = 0.0f;
  }
  __syncthreads();

  float px[PPT], py[PPT], pz[PPT], dst[PPT];
  unsigned ilo[PPT];
#pragma unroll
  for (int k = 0; k < PPT; ++k) {
    int p = t + (k << 9);
    px[k] = sxyz4[p * 4 + 0];
    py[k] = sxyz4[p * 4 + 1];
    pz[k] = sxyz4[p * 4 + 2];
    dst[k] = 1e10f;                    // matches reference init 1e10
    ilo[k] = ~(unsigned)p;             // tie-break: lowest index wins
  }

  int farh0 = 0, farh1 = 0;            // register far-history for final writes
  int far = 0;                         // reference: farthest starts at 0
  for (int n = 0; n < NQ; ++n) {
    const float4 c = *(const float4*)(sxyz4 + far * 4);   // broadcast b128
    if (t == 0)                        // publish: one word, relaxed, agent
      __hip_atomic_store(ws_idx + (b << 10) + n, far,
                         __ATOMIC_RELAXED, __HIP_MEMORY_SCOPE_AGENT);
    if ((n & (FPS_T - 1)) == t) {      // history in registers
      if (n >> 9) farh1 = far; else farh0 = far;
    }

    double kk[PPT];
#pragma unroll
    for (int k = 0; k < PPT; ++k) {
      // EXACT reference order: (dx*dx + dy*dy) + dz*dz, no FMA contraction
      float dx = __fsub_rn(px[k], c.x);
      float dy = __fsub_rn(py[k], c.y);
      float dz = __fsub_rn(pz[k], c.z);
      float d2 = __fadd_rn(__fadd_rn(__fmul_rn(dx, dx), __fmul_rn(dy, dy)),
                           __fmul_rn(dz, dz));
      float dm = fminf(dst[k], d2);
      dst[k] = dm;
      kk[k] = __longlong_as_double((long long)(
          ((unsigned long long)__float_as_uint(dm) << 32) | ilo[k]));
    }
    double m0 = fmax(kk[0], kk[1]);
    double m1 = fmax(kk[2], kk[3]);
    double m2 = fmax(kk[4], kk[5]);
    double m3 = fmax(kk[6], kk[7]);
    double best = fmax(fmax(m0, m1), fmax(m2, m3));
    best = wave_keymax(best);          // lane 63 has wave max

    long long bi = __double_as_longlong(best);
    unsigned blo = (unsigned)__builtin_amdgcn_readlane(
        (int)(unsigned)((unsigned long long)bi & 0xffffffffull), 63);
    unsigned bhi = (unsigned)__builtin_amdgcn_readlane(
        (int)(unsigned)((unsigned long long)bi >> 32), 63);
    double wkey = __longlong_as_double(
        (long long)(((unsigned long long)bhi << 32) | blo));

    const int par = n & 1;             // double-buffered slots
    if (lane == 0) swk[par][wave] = wkey;
    __syncthreads();

    const double2* sp = (const double2*)swk[par];
    double2 a0 = sp[0], a1 = sp[1], a2 = sp[2], a3 = sp[3];
    double mk = fmax(fmax(fmax(a0.x, a0.y), fmax(a1.x, a1.y)),
                     fmax(fmax(a2.x, a2.y), fmax(a3.x, a3.y)));
    far = (int)(~(unsigned)((unsigned long long)__double_as_longlong(mk)));
  }

  // write all 1024 centroids once (bit-exact copies of input rows)
  {
    float4 c0 = *(const float4*)(sxyz4 + farh0 * 4);
    float* o0 = out_newxyz + ((size_t)b * NQ + t) * 3;
    o0[0] = c0.x; o0[1] = c0.y; o0[2] = c0.z;
    float4 c1 = *(const float4*)(sxyz4 + farh1 * 4);
    float* o1 = out_newxyz + ((size_t)b * NQ + FPS_T + t) * 3;
    o1[0] = c1.x; o1[1] = c1.y; o1[2] = c1.z;
  }
}

// ===========================================================================
// SA per-query machinery (r5-proven math)
// ===========================================================================
__device__ __forceinline__ void mlp_acc(float* __restrict__ acc,
                                        const float* __restrict__ XTb,
                                        const float* __restrict__ wg,
                                        int ldw, int nk, int fg, int sg)
{
#pragma unroll
  for (int i = 0; i < 32; ++i) acc[i] = 0.0f;
  const float* xrow = XTb + sg * 4;
  const float* wrow = wg + fg * 8;
#pragma unroll 4
  for (int k = 0; k < nk; ++k) {
    const float4 x  = *(const float4*)(xrow + k * XTW);
    const float4 wa = *(const float4*)(wrow + (size_t)k * ldw);
    const float4 wb = *(const float4*)(wrow + (size_t)k * ldw + 4);
    acc[0]  = fmaf(wa.x, x.x, acc[0]);  acc[1]  = fmaf(wa.x, x.y, acc[1]);
    acc[2]  = fmaf(wa.x, x.z, acc[2]);  acc[3]  = fmaf(wa.x, x.w, acc[3]);
    acc[4]  = fmaf(wa.y, x.x, acc[4]);  acc[5]  = fmaf(wa.y, x.y, acc[5]);
    acc[6]  = fmaf(wa.y, x.z, acc[6]);  acc[7]  = fmaf(wa.y, x.w, acc[7]);
    acc[8]  = fmaf(wa.z, x.x, acc[8]);  acc[9]  = fmaf(wa.z, x.y, acc[9]);
    acc[10] = fmaf(wa.z, x.z, acc[10]); acc[11] = fmaf(wa.z, x.w, acc[11]);
    acc[12] = fmaf(wa.w, x.x, acc[12]); acc[13] = fmaf(wa.w, x.y, acc[13]);
    acc[14] = fmaf(wa.w, x.z, acc[14]); acc[15] = fmaf(wa.w, x.w, acc[15]);
    acc[16] = fmaf(wb.x, x.x, acc[16]); acc[17] = fmaf(wb.x, x.y, acc[17]);
    acc[18] = fmaf(wb.x, x.z, acc[18]); acc[19] = fmaf(wb.x, x.w, acc[19]);
    acc[20] = fmaf(wb.y, x.x, acc[20]); acc[21] = fmaf(wb.y, x.y, acc[21]);
    acc[22] = fmaf(wb.y, x.z, acc[22]); acc[23] = fmaf(wb.y, x.w, acc[23]);
    acc[24] = fmaf(wb.z, x.x, acc[24]); acc[25] = fmaf(wb.z, x.y, acc[25]);
    acc[26] = fmaf(wb.z, x.z, acc[26]); acc[27] = fmaf(wb.z, x.w, acc[27]);
    acc[28] = fmaf(wb.w, x.x, acc[28]); acc[29] = fmaf(wb.w, x.y, acc[29]);
    acc[30] = fmaf(wb.w, x.z, acc[30]); acc[31] = fmaf(wb.w, x.w, acc[31]);
  }
}

__device__ __forceinline__ void store_layer(const float* __restrict__ acc,
                                            float* __restrict__ XTb,
                                            const float* __restrict__ g,
                                            const float* __restrict__ bi,
                                            const float* __restrict__ be,
                                            int fg, int sg, float RSQ)
{
  const float4 ga = *(const float4*)(g  + fg * 8);
  const float4 gb = *(const float4*)(g  + fg * 8 + 4);
  const float4 ba = *(const float4*)(bi + fg * 8);
  const float4 bb = *(const float4*)(bi + fg * 8 + 4);
  const float4 ea = *(const float4*)(be + fg * 8);
  const float4 eb = *(const float4*)(be + fg * 8 + 4);
  float sv[8] = {ga.x * RSQ, ga.y * RSQ, ga.z * RSQ, ga.w * RSQ,
                 gb.x * RSQ, gb.y * RSQ, gb.z * RSQ, gb.w * RSQ};
  float bv[8] = {ba.x, ba.y, ba.z, ba.w, bb.x, bb.y, bb.z, bb.w};
  float ev[8] = {ea.x, ea.y, ea.z, ea.w, eb.x, eb.y, eb.z, eb.w};
#pragma unroll
  for (int j = 0; j < 8; ++j) {
    float tv = fmaf(bv[j], sv[j], ev[j]);
    float4 h;
    h.x = fmaxf(fmaf(acc[j * 4 + 0], sv[j], tv), 0.0f);
    h.y = fmaxf(fmaf(acc[j * 4 + 1], sv[j], tv), 0.0f);
    h.z = fmaxf(fmaf(acc[j * 4 + 2], sv[j], tv), 0.0f);
    h.w = fmaxf(fmaf(acc[j * 4 + 3], sv[j], tv), 0.0f);
    *(float4*)(XTb + (fg * 8 + j) * XTW + sg * 4) = h;
  }
}

__device__ void worker_query(int q, int idx,
    const float* __restrict__ xyz, const float* __restrict__ pts,
    const float* __restrict__ w0, const float* __restrict__ b0,
    const float* __restrict__ g0, const float* __restrict__ be0,
    const float* __restrict__ w1, const float* __restrict__ b1,
    const float* __restrict__ g1, const float* __restrict__ be1,
    const float* __restrict__ w2, const float* __restrict__ b2,
    const float* __restrict__ g2, const float* __restrict__ be2,
    float* __restrict__ outp, float* __restrict__ XT, int* __restrict__ bidx,
    int lane)
{
  const int b = q >> 10;
  const float* xb = xyz + (size_t)b * NPTS * 3;
  // centroid from the immutable input via the published index: bit-identical
  // to newxyz[q], immune to cache staleness (xyz never written on GPU).
  const float cx = xb[idx * 3 + 0];
  const float cy = xb[idx * 3 + 1];
  const float cz = xb[idx * 3 + 2];

  // ---- ball query (pipelined 2 ahead): first <=32 in-radius, ascending ----
  int cnt = 0;
  float x0 = xb[lane * 3 + 0], y0 = xb[lane * 3 + 1], z0 = xb[lane * 3 + 2];
  float x1 = xb[(64 + lane) * 3 + 0], y1 = xb[(64 + lane) * 3 + 1],
        z1 = xb[(64 + lane) * 3 + 2];
  for (int ch = 0; ch < 64; ++ch) {
    const int an = (min(ch + 2, 63) << 6) | lane;
    float nx = xb[an * 3 + 0], ny = xb[an * 3 + 1], nz = xb[an * 3 + 2];
    float dx = __fsub_rn(cx, x0);
    float dy = __fsub_rn(cy, y0);
    float dz = __fsub_rn(cz, z0);
    float d2 = __fadd_rn(__fadd_rn(__fmul_rn(dx, dx), __fmul_rn(dy, dy)),
                         __fmul_rn(dz, dz));
    bool in = d2 < 0.04f;
    unsigned long long bal = __ballot(in);
    int pos = cnt + (int)__popcll(bal & ((1ull << lane) - 1ull));
    if (in && pos < 32) bidx[pos] = (ch << 6) | lane;
    cnt += (int)__popcll(bal);
    x0 = x1; y0 = y1; z0 = z1;
    x1 = nx; y1 = ny; z1 = nz;
    if (cnt >= 32) break;
  }
  if (cnt > 32) cnt = 32;
  int i0 = bidx[0];
  if (lane < 32 && lane >= cnt) bidx[lane] = i0;
  __builtin_amdgcn_wave_barrier();

  // ---- gather into X^T[k][s] ----
  const int s  = lane & 31;
  const int kc = lane >> 5;
  const int is = bidx[s];
  const float4* pr4 = (const float4*)(pts + ((size_t)(b * NPTS + is)) * 64 + kc * 32);
  float* xcol = XT + s;
#pragma unroll
  for (int c = 0; c < 8; ++c) {
    float4 v = pr4[c];
    xcol[(kc * 32 + c * 4 + 0) * XTW] = v.x;
    xcol[(kc * 32 + c * 4 + 1) * XTW] = v.y;
    xcol[(kc * 32 + c * 4 + 2) * XTW] = v.z;
    xcol[(kc * 32 + c * 4 + 3) * XTW] = v.w;
  }
  if (kc == 0) {
    float ax = xb[is * 3 + 0], ay = xb[is * 3 + 1], az = xb[is * 3 + 2];
    xcol[64 * XTW] = ax - cx;
    xcol[65 * XTW] = ay - cy;
    xcol[66 * XTW] = az - cz;
  }
  __builtin_amdgcn_wave_barrier();

  const int fg = lane >> 3;
  const int sg = lane & 7;
  const float RSQ = rsqrtf(1.0f + 0.001f);
  float acc[32];

  mlp_acc(acc, XT, w0, 64, 67, fg, sg);
  store_layer(acc, XT, g0, b0, be0, fg, sg, RSQ);
  __builtin_amdgcn_wave_barrier();

  mlp_acc(acc, XT, w1, 64, 64, fg, sg);
  store_layer(acc, XT, g1, b1, be1, fg, sg, RSQ);
  __builtin_amdgcn_wave_barrier();

#pragma unroll
  for (int pass = 0; pass < 2; ++pass) {
    const int fofs = pass << 6;
    mlp_acc(acc, XT, w2 + fofs, 128, 64, fg, sg);
    const float4 ga = *(const float4*)(g2  + fofs + fg * 8);
    const float4 gb = *(const float4*)(g2  + fofs + fg * 8 + 4);
    const float4 ba = *(const float4*)(b2  + fofs + fg * 8);
    const float4 bb = *(const float4*)(b2  + fofs + fg * 8 + 4);
    const float4 ea = *(const float4*)(be2 + fofs + fg * 8);
    const float4 eb = *(const float4*)(be2 + fofs + fg * 8 + 4);
    float sv[8] = {ga.x * RSQ, ga.y * RSQ, ga.z * RSQ, ga.w * RSQ,
                   gb.x * RSQ, gb.y * RSQ, gb.z * RSQ, gb.w * RSQ};
    float bv[8] = {ba.x, ba.y, ba.z, ba.w, bb.x, bb.y, bb.z, bb.w};
    float ev[8] = {ea.x, ea.y, ea.z, ea.w, eb.x, eb.y, eb.z, eb.w};
    float r[8];
#pragma unroll
    for (int j = 0; j < 8; ++j) {
      float mx = fmaxf(fmaxf(acc[j * 4 + 0], acc[j * 4 + 1]),
                       fmaxf(acc[j * 4 + 2], acc[j * 4 + 3]));
      float mn = fminf(fminf(acc[j * 4 + 0], acc[j * 4 + 1]),
                       fminf(acc[j * 4 + 2], acc[j * 4 + 3]));
      mx = fmaxf(mx, dppq<0xB1>(mx));
      mx = fmaxf(mx, dppq<0x4E>(mx));
      mx = fmaxf(mx, dppq<0x141>(mx));
      mn = fminf(mn, dppq<0xB1>(mn));
      mn = fminf(mn, dppq<0x4E>(mn));
      mn = fminf(mn, dppq<0x141>(mn));
      float tv = fmaf(bv[j], sv[j], ev[j]);
      float m  = (sv[j] >= 0.0f) ? mx : mn;    // maxpool commutes with affine
      r[j] = fmaxf(fmaf(sv[j], m, tv), 0.0f);
    }
    if (sg == 0) {
      float* o = outp + (size_t)q * 128 + fofs + fg * 8;
      *(float4*)(o)     = make_float4(r[0], r[1], r[2], r[3]);
      *(float4*)(o + 4) = make_float4(r[4], r[5], r[6], r[7]);
    }
  }
}

// ===========================================================================
// Fused kernel: 248 blocks x 512 thr, 84 KB LDS => 1 block/CU => ALL blocks
// co-resident regardless of dispatch order (no deadlock; fps CUs unshared).
// Blocks 0..7: FPS.  Blocks 8..247: 8 persistent worker waves each; wave W
// handles queries g = W, W+1920, ... — spin (s_sleep, bounded) on the
// published index, then run ball-query+MLP.
// ===========================================================================
__global__ __launch_bounds__(FPS_T, 1) void fused_kernel(
    const float* __restrict__ xyz, const float* __restrict__ pts,
    const float* __restrict__ w0, const float* __restrict__ b0,
    const float* __restrict__ g0, const float* __restrict__ be0,
    const float* __restrict__ w1, const float* __restrict__ b1,
    const float* __restrict__ g1, const float* __restrict__ be1,
    const float* __restrict__ w2, const float* __restrict__ b2,
    const float* __restrict__ g2, const float* __restrict__ be2,
    float* __restrict__ newxyz, float* __restrict__ newpts,
    int* __restrict__ ws_idx)
{
  __shared__ __align__(16) char smem[SMEM_BYTES];

  if (blockIdx.x < FPS_NB) {
    fps_role(xyz, newxyz, ws_idx, smem);
    return;
  }

  const int lane = threadIdx.x & 63;
  const int wave = threadIdx.x >> 6;
  char* sl = smem + wave * WSLICE;
  float* XT  = (float*)sl;           // 67*36*4 = 9648 B
  int* bidx  = (int*)(sl + 9648);    // 128 B

  const int W = (blockIdx.x - FPS_NB) * 8 + wave;
  for (int g = W; g < NB * NQ; g += NWRK) {
    const int b = g & 7;             // q=(b<<10)|n swizzle
    const int n = g >> 3;
    const int q = (b << 10) | n;

    const int* slot = ws_idx + q;
    int idx = __hip_atomic_load(slot, __ATOMIC_RELAXED, __HIP_MEMORY_SCOPE_AGENT);
    int spins = 0;
    while ((unsigned)idx >= (unsigned)NPTS) {       // sentinel/poison = wait
      __builtin_amdgcn_s_sleep(16);
      idx = __hip_atomic_load(slot, __ATOMIC_RELAXED, __HIP_MEMORY_SCOPE_AGENT);
      if (++spins > 32768) { idx &= (NPTS - 1); break; }  // bounded: no hang
    }

    worker_query(q, idx, xyz, pts, w0, b0, g0, be0, w1, b1, g1, be1,
                 w2, b2, g2, be2, newpts, XT, bidx, lane);
  }
}

// ===========================================================================
extern "C" void kernel_launch(void* const* d_in, const int* in_sizes, int n_in,
                              void* d_out, int out_size, void* d_ws, size_t ws_size,
                              hipStream_t stream)
{
  const float* xyz = (const float*)d_in[0];
  const float* pts = (const float*)d_in[1];
  const float* w0  = (const float*)d_in[2];
  const float* b0  = (const float*)d_in[3];
  const float* g0  = (const float*)d_in[4];
  const float* be0 = (const float*)d_in[5];
  const float* w1  = (const float*)d_in[6];
  const float* b1  = (const float*)d_in[7];
  const float* g1  = (const float*)d_in[8];
  const float* be1 = (const float*)d_in[9];
  const float* w2  = (const float*)d_in[10];
  const float* b2  = (const float*)d_in[11];
  const float* g2  = (const float*)d_in[12];
  const float* be2 = (const float*)d_in[13];

  float* out    = (float*)d_out;
  float* newxyz = out;                    // 8*1024*3
  float* newpts = out + NB * NQ * 3;      // 8*1024*128
  int*   ws_idx = (int*)d_ws;             // 8192 published indices

  // sentinel-fill the mailbox (0xAA... is an invalid index)
  hipMemsetAsync(d_ws, 0xAA, (size_t)NB * NQ * sizeof(int), stream);

  hipLaunchKernelGGL(fused_kernel, dim3(FPS_NB + WRK_NB), dim3(FPS_T), 0, stream,
                     xyz, pts, w0, b0, g0, be0, w1, b1, g1, be1,
                     w2, b2, g2, be2, newxyz, newpts, ws_idx);
}